// Round 1
// baseline (281.319 us; speedup 1.0000x reference)
//
#include <hip/hip_runtime.h>
#include <math.h>

// B=4, T=2048, E=1024, H*D=1024; R = B*T = 8192.  K is always 1024.
#define R_ROWS 8192
#define T_SEQ  2048
#define E_DIM  1024
#define KC     32          // K/32 chunks

typedef __attribute__((ext_vector_type(8))) short short8;
typedef __attribute__((ext_vector_type(4))) float f32x4;

__device__ __forceinline__ ushort f2bf(float f) {
  uint u = __float_as_uint(f);
  u += 0x7FFFu + ((u >> 16) & 1u);   // round-to-nearest-even
  return (ushort)(u >> 16);
}
__device__ __forceinline__ float bf2f(ushort h) {
  return __uint_as_float(((uint)h) << 16);
}

// ---------------------------------------------------------------------------
// MFMA A/B fragment layout for a [R][1024] bf16 matrix:
//   off(r,k) = (((r>>4)*KC + (k>>5))*4 + ((k>>3)&3))*128 + (r&15)*8 + (k&7)
// ---------------------------------------------------------------------------

// fp32 [R][1024] -> (hi, lo) bf16 fragment layout. One thread = one 16B chunk.
__global__ __launch_bounds__(256) void cvt_split_frag(
    const float* __restrict__ in, ushort* __restrict__ hi,
    ushort* __restrict__ lo, int n)
{
  int g = blockIdx.x * 256 + threadIdx.x;
  if (g >= n) return;
  const int l = g & 15, h = (g >> 4) & 3;
  const int pq = g >> 6;
  const int q = pq & (KC - 1), p = pq >> 5;
  const size_t src = (size_t)(p * 16 + l) * 1024 + q * 32 + h * 8;
  const float4 v0 = *(const float4*)&in[src];
  const float4 v1 = *(const float4*)&in[src + 4];
  ushort hh[8], ll[8];
  const float v[8] = {v0.x, v0.y, v0.z, v0.w, v1.x, v1.y, v1.z, v1.w};
#pragma unroll
  for (int e = 0; e < 8; ++e) {
    hh[e] = f2bf(v[e]);
    ll[e] = f2bf(v[e] - bf2f(hh[e]));
  }
  *(uint4*)&hi[(size_t)g * 8] = *(const uint4*)hh;
  *(uint4*)&lo[(size_t)g * 8] = *(const uint4*)ll;
}

// Transposed split cvt: logical matrix is in^T.  Frag row rr = column of `in`,
// reduction index = row of `in`.  Used for wjv (M = wo @ wjv contracts over
// wjv's leading dim).  Reads are coalesced across the 16-lane groups.
__global__ __launch_bounds__(256) void cvt_splitT_frag(
    const float* __restrict__ in, ushort* __restrict__ hi,
    ushort* __restrict__ lo, int n)
{
  int g = blockIdx.x * 256 + threadIdx.x;
  if (g >= n) return;
  const int l = g & 15, h = (g >> 4) & 3;
  const int pq = g >> 6;
  const int q = pq & (KC - 1), p = pq >> 5;
  const int rr = p * 16 + l;          // logical row (k index of M's B-side)
  const int cc = q * 32 + h * 8;      // reduction col (e index)
  ushort hh[8], ll[8];
#pragma unroll
  for (int e = 0; e < 8; ++e) {
    const float v = in[(size_t)(cc + e) * 1024 + rr];
    hh[e] = f2bf(v);
    ll[e] = f2bf(v - bf2f(hh[e]));
  }
  *(uint4*)&hi[(size_t)g * 8] = *(const uint4*)hh;
  *(uint4*)&lo[(size_t)g * 8] = *(const uint4*)ll;
}

// ---------------------------------------------------------------------------
// Split-bf16 sc kernel, LDS-FREE K-loop (unchanged).
// ---------------------------------------------------------------------------
struct Frags { short8 ah[4], al[4], bh[4], bl[4]; };

__global__ __launch_bounds__(256, 2) void gemm_sq_direct(
    const ushort* __restrict__ xh, const ushort* __restrict__ xl,
    const ushort* __restrict__ wh, const ushort* __restrict__ wl,
    float* __restrict__ sc_raw)
{
  const int tid = threadIdx.x;
  const int m0 = blockIdx.y * 128, n0 = blockIdx.x * 128;
  const int wave = tid >> 6, lane = tid & 63;
  const int l15 = lane & 15, lq = lane >> 4;
  const int wm = (wave & 1) * 64, wn = (wave >> 1) * 64;

  size_t aoff[4], boff[4];
#pragma unroll
  for (int i = 0; i < 4; ++i)
    aoff[i] = ((size_t)(((m0 + wm) >> 4) + i) * KC * 4 + lq) * 128 + l15 * 8;
#pragma unroll
  for (int j = 0; j < 4; ++j)
    boff[j] = ((size_t)(((n0 + wn) >> 4) + j) * KC * 4 + lq) * 128 + l15 * 8;

  f32x4 acc[4][4] = {};
  Frags f0, f1;

  auto load = [&](Frags& f, int q) {
    const size_t dq = (size_t)q * 512;
#pragma unroll
    for (int i = 0; i < 4; ++i) {
      f.ah[i] = *(const short8*)(xh + aoff[i] + dq);
      f.al[i] = *(const short8*)(xl + aoff[i] + dq);
    }
#pragma unroll
    for (int j = 0; j < 4; ++j) {
      f.bh[j] = *(const short8*)(wh + boff[j] + dq);
      f.bl[j] = *(const short8*)(wl + boff[j] + dq);
    }
  };
  auto step = [&](const Frags& f) {
#pragma unroll
    for (int i = 0; i < 4; ++i)
#pragma unroll
      for (int j = 0; j < 4; ++j) {
        acc[i][j] = __builtin_amdgcn_mfma_f32_16x16x32_bf16(f.ah[i], f.bh[j], acc[i][j], 0, 0, 0);
        acc[i][j] = __builtin_amdgcn_mfma_f32_16x16x32_bf16(f.ah[i], f.bl[j], acc[i][j], 0, 0, 0);
        acc[i][j] = __builtin_amdgcn_mfma_f32_16x16x32_bf16(f.al[i], f.bh[j], acc[i][j], 0, 0, 0);
      }
  };

  load(f0, 0);
#pragma unroll 1
  for (int q = 0; q < KC; q += 2) {
    load(f1, q + 1);
    step(f0);
    if (q + 2 < KC) load(f0, q + 2);
    step(f1);
  }

  __shared__ float red[128][33];
#pragma unroll
  for (int i = 0; i < 4; ++i)
#pragma unroll
    for (int r = 0; r < 4; ++r) {
      const int row = wm + i * 16 + lq * 4 + r;
      float s = 0.f;
#pragma unroll
      for (int j = 0; j < 4; ++j) s += acc[i][j][r] * acc[i][j][r];
      red[row][(l15 << 1) | (wave >> 1)] = s;
    }
  __syncthreads();
  if (tid < 128) {
    float s = 0.f;
#pragma unroll
    for (int c = 0; c < 32; ++c) s += red[tid][c];
    atomicAdd(&sc_raw[m0 + tid], s);
  }
}

// ---------------------------------------------------------------------------
// M = wo @ wjv, split-precision direct-frag GEMM (fp32-accurate), output bf16
// row-major Mh[f][k].  A = wo split frags, B = wjv^T split frags.  8x8 grid.
// ---------------------------------------------------------------------------
__global__ __launch_bounds__(256, 2) void gemm_m_split(
    const ushort* __restrict__ ah_, const ushort* __restrict__ al_,
    const ushort* __restrict__ bh_, const ushort* __restrict__ bl_,
    ushort* __restrict__ Mh)
{
  const int tid = threadIdx.x;
  const int m0 = blockIdx.y * 128, n0 = blockIdx.x * 128;
  const int wave = tid >> 6, lane = tid & 63;
  const int l15 = lane & 15, lq = lane >> 4;
  const int wm = (wave & 1) * 64, wn = (wave >> 1) * 64;

  size_t aoff[4], boff[4];
#pragma unroll
  for (int i = 0; i < 4; ++i)
    aoff[i] = ((size_t)(((m0 + wm) >> 4) + i) * KC * 4 + lq) * 128 + l15 * 8;
#pragma unroll
  for (int j = 0; j < 4; ++j)
    boff[j] = ((size_t)(((n0 + wn) >> 4) + j) * KC * 4 + lq) * 128 + l15 * 8;

  f32x4 acc[4][4] = {};
  Frags f0, f1;

  auto load = [&](Frags& f, int q) {
    const size_t dq = (size_t)q * 512;
#pragma unroll
    for (int i = 0; i < 4; ++i) {
      f.ah[i] = *(const short8*)(ah_ + aoff[i] + dq);
      f.al[i] = *(const short8*)(al_ + aoff[i] + dq);
    }
#pragma unroll
    for (int j = 0; j < 4; ++j) {
      f.bh[j] = *(const short8*)(bh_ + boff[j] + dq);
      f.bl[j] = *(const short8*)(bl_ + boff[j] + dq);
    }
  };
  auto step = [&](const Frags& f) {
#pragma unroll
    for (int i = 0; i < 4; ++i)
#pragma unroll
      for (int j = 0; j < 4; ++j) {
        acc[i][j] = __builtin_amdgcn_mfma_f32_16x16x32_bf16(f.ah[i], f.bh[j], acc[i][j], 0, 0, 0);
        acc[i][j] = __builtin_amdgcn_mfma_f32_16x16x32_bf16(f.ah[i], f.bl[j], acc[i][j], 0, 0, 0);
        acc[i][j] = __builtin_amdgcn_mfma_f32_16x16x32_bf16(f.al[i], f.bh[j], acc[i][j], 0, 0, 0);
      }
  };

  load(f0, 0);
#pragma unroll 1
  for (int q = 0; q < KC; q += 2) {
    load(f1, q + 1);
    step(f0);
    if (q + 2 < KC) load(f0, q + 2);
    step(f1);
  }

#pragma unroll
  for (int i = 0; i < 4; ++i)
#pragma unroll
    for (int j = 0; j < 4; ++j) {
      const int mb = m0 + wm + i * 16 + lq * 4;
      const int nb = n0 + wn + j * 16 + l15;
#pragma unroll
      for (int r = 0; r < 4; ++r)
        Mh[(size_t)(mb + r) * E_DIM + nb] = f2bf(acc[i][j][r]);
    }
}

// ---------------------------------------------------------------------------
// sc = sc_raw/32; pmax = inclusive prefix max per batch (unchanged).
// ---------------------------------------------------------------------------
__global__ __launch_bounds__(1024) void scan_max(
    const float* __restrict__ sc_raw, float* __restrict__ sc,
    float* __restrict__ pmax)
{
  const int b = blockIdx.x;
  __shared__ float b0[T_SEQ];
  __shared__ float b1[T_SEQ];
  const int tid = threadIdx.x;
  for (int i = tid; i < T_SEQ; i += 1024) {
    const float v = sc_raw[b*T_SEQ + i] * 0.03125f;
    b0[i] = v;
    sc[b*T_SEQ + i] = v;
  }
  __syncthreads();
  float* src = b0; float* dst = b1;
  for (int off = 1; off < T_SEQ; off <<= 1) {
    for (int i = tid; i < T_SEQ; i += 1024)
      dst[i] = (i >= off) ? fmaxf(src[i], src[i - off]) : src[i];
    __syncthreads();
    float* tmp = src; src = dst; dst = tmp;
  }
  for (int i = tid; i < T_SEQ; i += 1024) pmax[b*T_SEQ + i] = src[i];
}

// ---------------------------------------------------------------------------
// bf16 MFMA NT GEMM, B-side direct from fragment layout (unchanged).
// ---------------------------------------------------------------------------
template<bool OUT_BF16>
__global__ __launch_bounds__(256) void gemm_bf16_bfrag(
    const ushort* __restrict__ A, const ushort* __restrict__ Bf,
    void* __restrict__ Cout, int N, int K)
{
  __shared__ ushort As[128][40];
  const int tid = threadIdx.x;
  const int m0 = blockIdx.y * 128, n0 = blockIdx.x * 128;
  const int wave = tid >> 6, lane = tid & 63;
  const int l15 = lane & 15, lq = lane >> 4;
  const int wm = (wave & 1) * 64, wn = (wave >> 1) * 64;
  const int srow = tid >> 2, scol = (tid & 3) * 8;
  const int Kc = K >> 5;

  f32x4 acc[4][4] = {};
  const ushort* Ap = A + (size_t)(m0 + srow) * K + scol;
  size_t boff[4];
#pragma unroll
  for (int j = 0; j < 4; ++j)
    boff[j] = ((size_t)(((n0 + wn) >> 4) + j) * Kc * 4 + lq) * 128 + l15 * 8;

  for (int q = 0; q < Kc; ++q) {
    const uint4 a0 = *(const uint4*)(Ap + q * 32);
    const uint4 a1 = *(const uint4*)(Ap + (size_t)64 * K + q * 32);
    short8 bfr[4];
#pragma unroll
    for (int j = 0; j < 4; ++j)
      bfr[j] = *(const short8*)(Bf + boff[j] + (size_t)q * 512);
    __syncthreads();
    *(uint4*)&As[srow     ][scol] = a0;
    *(uint4*)&As[srow + 64][scol] = a1;
    __syncthreads();
    short8 af[4];
#pragma unroll
    for (int i = 0; i < 4; ++i)
      af[i] = *(const short8*)&As[wm + i*16 + l15][lq*8];
#pragma unroll
    for (int i = 0; i < 4; ++i)
#pragma unroll
      for (int j = 0; j < 4; ++j)
        acc[i][j] = __builtin_amdgcn_mfma_f32_16x16x32_bf16(af[i], bfr[j], acc[i][j], 0, 0, 0);
  }

#pragma unroll
  for (int i = 0; i < 4; ++i)
#pragma unroll
    for (int j = 0; j < 4; ++j) {
      const int mb = m0 + wm + i*16 + lq*4;
      const int nb = n0 + wn + j*16 + l15;
#pragma unroll
      for (int r = 0; r < 4; ++r) {
        if (OUT_BF16)
          ((ushort*)Cout)[(size_t)(mb + r) * N + nb] = f2bf(acc[i][j][r]);
        else
          ((float*)Cout)[(size_t)(mb + r) * N + nb] = acc[i][j][r];
      }
    }
}

// ---------------------------------------------------------------------------
// Fused causal rank-1 attention.  Now consumes W^T = (val @ wo^T)^T and writes
// the FINAL fp32 output directly (out-GEMM eliminated via reassociation).
// ---------------------------------------------------------------------------
__global__ __launch_bounds__(512) void attn_mfma(
    const ushort* __restrict__ valT, const float* __restrict__ sc,
    const float* __restrict__ pmax, float* __restrict__ outp)
{
  __shared__ float scs_all[T_SEQ];
  __shared__ ushort p[2][128][72];
  __shared__ float zsh[128][4];
  __shared__ float zinv[128];

  const int b  = blockIdx.z;
  const int e0 = blockIdx.x * 128;
  const int tid = threadIdx.x;
  const int wave = tid >> 6, lane = tid & 63;
  const int l15 = lane & 15, lq = lane >> 4;
  const int wm = (wave & 1) * 64;
  const int wn = (wave >> 1) * 32;
  const int bT = b * T_SEQ;

  *(float4*)&scs_all[tid * 4] = *(const float4*)&sc[bT + tid * 4];
  __syncthreads();

  const int prow = tid >> 2;
  const int pc = (tid & 3) * 16;

#pragma unroll 1
  for (int ph = 0; ph < 2; ++ph) {
    const int ty = ph == 0 ? (15 - (int)blockIdx.y) : (int)blockIdx.y;
    const int t0 = ty * 128;
    const int nchunk = 2 * ty + 2;

    const int tglob = t0 + prow;
    const float st = sc[bT + tglob];
    const float pm = pmax[bT + tglob];

    f32x4 acc[4][2] = {};
    float zp = 0.f;

    auto pgen = [&](int c, int buf) -> float {
      const int s0 = c * 64;
      float sv[16];
#pragma unroll
      for (int q = 0; q < 4; ++q)
        *(float4*)&sv[q*4] = *(const float4*)&scs_all[s0 + pc + q*4];
      ushort tmp[16];
      float z = 0.f;
#pragma unroll
      for (int k = 0; k < 16; ++k) {
        const int sg = s0 + pc + k;
        float pe = 0.f;
        if (sg <= tglob) pe = __expf(st * (sv[k] - pm));
        tmp[k] = f2bf(pe);
        z += pe;                       // fp32 accumulate (no bf16 round-trip)
      }
      *(uint4*)&p[buf][prow][pc    ] = *(const uint4*)&tmp[0];
      *(uint4*)&p[buf][prow][pc + 8] = *(const uint4*)&tmp[8];
      return z;
    };

    auto loadB = [&](short8* dst, int c) {
#pragma unroll
      for (int j = 0; j < 2; ++j)
#pragma unroll
        for (int ksi = 0; ksi < 2; ++ksi)
          dst[j*2 + ksi] = *(const short8*)&valT[
              (size_t)(e0 + wn + j*16 + l15) * R_ROWS + bT + c*64 + ksi*32 + lq*8];
    };

    auto mstep = [&](int buf, const short8* bfr) {
#pragma unroll
      for (int ksi = 0; ksi < 2; ++ksi) {
        short8 af[4];
#pragma unroll
        for (int i = 0; i < 4; ++i)
          af[i] = *(const short8*)&p[buf][wm + i*16 + l15][ksi*32 + lq*8];
#pragma unroll
        for (int i = 0; i < 4; ++i)
#pragma unroll
          for (int j = 0; j < 2; ++j)
            acc[i][j] = __builtin_amdgcn_mfma_f32_16x16x32_bf16(
                af[i], bfr[j*2 + ksi], acc[i][j], 0, 0, 0);
      }
    };

    short8 bA[4], bB[4];
    zp += pgen(0, 0);
    loadB(bA, 0);
    __syncthreads();

#pragma unroll 1
    for (int c = 0; c < nchunk; ++c) {
      if ((c & 1) == 0) {
        if (c + 1 < nchunk) { loadB(bB, c + 1); zp += pgen(c + 1, 1); }
        mstep(0, bA);
      } else {
        if (c + 1 < nchunk) { loadB(bA, c + 1); zp += pgen(c + 1, 0); }
        mstep(1, bB);
      }
      __syncthreads();
    }

    zsh[prow][tid & 3] = zp;
    __syncthreads();
    if (tid < 128)
      zinv[tid] = 1.0f / (zsh[tid][0] + zsh[tid][1] + zsh[tid][2] + zsh[tid][3]);
    __syncthreads();

#pragma unroll
    for (int i = 0; i < 4; ++i)
#pragma unroll
      for (int j = 0; j < 2; ++j) {
        const int nb = e0 + wn + j*16 + l15;
#pragma unroll
        for (int r = 0; r < 4; ++r) {
          const int ml = wm + i*16 + lq*4 + r;
          outp[(size_t)(bT + t0 + ml) * E_DIM + nb] = acc[i][j][r] * zinv[ml];
        }
      }
    __syncthreads();
  }
}

// ---------------------------------------------------------------------------
extern "C" void kernel_launch(void* const* d_in, const int* in_sizes, int n_in,
                              void* d_out, int out_size, void* d_ws, size_t ws_size,
                              hipStream_t stream) {
  (void)in_sizes; (void)n_in; (void)out_size; (void)ws_size;
  const float* x   = (const float*)d_in[0];
  const float* wj  = (const float*)d_in[1];
  const float* wjv = (const float*)d_in[2];
  const float* wo  = (const float*)d_in[3];
  float* out = (float*)d_out;

  ushort* xh_f  = (ushort*)d_ws;                        // 16 MB frag
  ushort* xl_f  = xh_f  + (size_t)R_ROWS * E_DIM;       // 16 MB frag; later WT
  ushort* bufA  = xl_f  + (size_t)R_ROWS * E_DIM;       // 2 MB: wo_h frag, then wj_h
  ushort* bufB  = bufA  + (size_t)E_DIM * E_DIM;        // 2 MB: wo_l frag, then wj_l
  ushort* bufC  = bufB  + (size_t)E_DIM * E_DIM;        // 2 MB: wjv^T_h frag
  ushort* bufD  = bufC  + (size_t)E_DIM * E_DIM;        // 2 MB: wjv^T_l frag
  ushort* Mh    = bufD  + (size_t)E_DIM * E_DIM;        // 2 MB: bf16 M = wo@wjv
  float* sc_raw = (float*)(Mh + (size_t)E_DIM * E_DIM);
  float* sc     = sc_raw + R_ROWS;
  float* pmax   = sc + R_ROWS;
  ushort* WT    = xl_f;    // xl_f dead after gemm_sq_direct (stream-serial)

  hipMemsetAsync(sc_raw, 0, R_ROWS * sizeof(float), stream);

  // --- M = wo @ wjv (split-precision, fp32-accurate), Mh = bf16(M) ---------
  cvt_split_frag <<<E_DIM*E_DIM/8/256, 256, 0, stream>>>(wo,  bufA, bufB, E_DIM*E_DIM/8);
  cvt_splitT_frag<<<E_DIM*E_DIM/8/256, 256, 0, stream>>>(wjv, bufC, bufD, E_DIM*E_DIM/8);
  gemm_m_split<<<dim3(E_DIM/128, E_DIM/128), 256, 0, stream>>>(bufA, bufB, bufC, bufD, Mh);

  // --- x and wj split frags (wj frags overwrite the dead wo frags) ---------
  cvt_split_frag<<<R_ROWS*E_DIM/8/256, 256, 0, stream>>>(x,  xh_f, xl_f, R_ROWS*E_DIM/8);
  cvt_split_frag<<<E_DIM*E_DIM/8/256, 256, 0, stream>>>(wj, bufA, bufB, E_DIM*E_DIM/8);

  // sc_raw[r] = ||x_r @ wj^T||^2  (split-bf16 MFMA, LDS-free direct frags)
  gemm_sq_direct<<<dim3(E_DIM/128, R_ROWS/128), 256, 0, stream>>>(
      xh_f, xl_f, bufA, bufB, sc_raw);
  scan_max<<<4, 1024, 0, stream>>>(sc_raw, sc, pmax);

  // WT[f][r] = sum_k Mh[f][k] * x[r][k]   == (val @ wo^T)^T, bf16
  gemm_bf16_bfrag<true><<<dim3(R_ROWS/128, E_DIM/128), 256, 0, stream>>>(
      Mh, xh_f, WT, R_ROWS, E_DIM);

  // attention applied to W, normalized, fp32 final output (out-GEMM fused away)
  attn_mfma<<<dim3(E_DIM/128, 8, 4), 512, 0, stream>>>(WT, sc, pmax, out);
}

// Round 2
// 275.172 us; speedup vs baseline: 1.0223x; 1.0223x over previous
//
#include <hip/hip_runtime.h>
#include <math.h>

// B=4, T=2048, E=1024, H*D=1024; R = B*T = 8192.  K is always 1024.
#define R_ROWS 8192
#define T_SEQ  2048
#define E_DIM  1024
#define KC     32          // K/32 chunks for K=1024
#define KCR    256         // K/32 chunks for K=8192 (WT frag layout)
// Packed P storage: per batch, supertile P (128 rows) has 8 rowblocks x (4P+4)
// chunks; total chunks = sum_{P=0..15} 8*(4P+4) = 4352; each chunk = 512 elems.
#define PBATCH_ELEMS ((size_t)4352 * 512)

typedef __attribute__((ext_vector_type(8))) short short8;
typedef __attribute__((ext_vector_type(4))) float f32x4;

__device__ __forceinline__ ushort f2bf(float f) {
  uint u = __float_as_uint(f);
  u += 0x7FFFu + ((u >> 16) & 1u);   // round-to-nearest-even
  return (ushort)(u >> 16);
}
__device__ __forceinline__ float bf2f(ushort h) {
  return __uint_as_float(((uint)h) << 16);
}

// ---------------------------------------------------------------------------
// MFMA A/B fragment layout for a [R][K] bf16 matrix (KCx = K/32):
//   off(r,k) = (((r>>4)*KCx + (k>>5))*4 + ((k>>3)&3))*128 + (r&15)*8 + (k&7)
// ---------------------------------------------------------------------------

// fp32 [R][1024] -> (hi, lo) bf16 fragment layout. One thread = one 16B chunk.
__global__ __launch_bounds__(256) void cvt_split_frag(
    const float* __restrict__ in, ushort* __restrict__ hi,
    ushort* __restrict__ lo, int n)
{
  int g = blockIdx.x * 256 + threadIdx.x;
  if (g >= n) return;
  const int l = g & 15, h = (g >> 4) & 3;
  const int pq = g >> 6;
  const int q = pq & (KC - 1), p = pq >> 5;
  const size_t src = (size_t)(p * 16 + l) * 1024 + q * 32 + h * 8;
  const float4 v0 = *(const float4*)&in[src];
  const float4 v1 = *(const float4*)&in[src + 4];
  ushort hh[8], ll[8];
  const float v[8] = {v0.x, v0.y, v0.z, v0.w, v1.x, v1.y, v1.z, v1.w};
#pragma unroll
  for (int e = 0; e < 8; ++e) {
    hh[e] = f2bf(v[e]);
    ll[e] = f2bf(v[e] - bf2f(hh[e]));
  }
  *(uint4*)&hi[(size_t)g * 8] = *(const uint4*)hh;
  *(uint4*)&lo[(size_t)g * 8] = *(const uint4*)ll;
}

// Transposed split cvt: logical matrix is in^T (used for wjv).
__global__ __launch_bounds__(256) void cvt_splitT_frag(
    const float* __restrict__ in, ushort* __restrict__ hi,
    ushort* __restrict__ lo, int n)
{
  int g = blockIdx.x * 256 + threadIdx.x;
  if (g >= n) return;
  const int l = g & 15, h = (g >> 4) & 3;
  const int pq = g >> 6;
  const int q = pq & (KC - 1), p = pq >> 5;
  const int rr = p * 16 + l;          // logical row (k index of M's B-side)
  const int cc = q * 32 + h * 8;      // reduction col (e index)
  ushort hh[8], ll[8];
#pragma unroll
  for (int e = 0; e < 8; ++e) {
    const float v = in[(size_t)(cc + e) * 1024 + rr];
    hh[e] = f2bf(v);
    ll[e] = f2bf(v - bf2f(hh[e]));
  }
  *(uint4*)&hi[(size_t)g * 8] = *(const uint4*)hh;
  *(uint4*)&lo[(size_t)g * 8] = *(const uint4*)ll;
}

// ---------------------------------------------------------------------------
// Split-bf16 sc kernel, LDS-FREE K-loop (unchanged from last round).
// ---------------------------------------------------------------------------
struct Frags { short8 ah[4], al[4], bh[4], bl[4]; };

__global__ __launch_bounds__(256, 2) void gemm_sq_direct(
    const ushort* __restrict__ xh, const ushort* __restrict__ xl,
    const ushort* __restrict__ wh, const ushort* __restrict__ wl,
    float* __restrict__ sc_raw)
{
  const int tid = threadIdx.x;
  const int m0 = blockIdx.y * 128, n0 = blockIdx.x * 128;
  const int wave = tid >> 6, lane = tid & 63;
  const int l15 = lane & 15, lq = lane >> 4;
  const int wm = (wave & 1) * 64, wn = (wave >> 1) * 64;

  size_t aoff[4], boff[4];
#pragma unroll
  for (int i = 0; i < 4; ++i)
    aoff[i] = ((size_t)(((m0 + wm) >> 4) + i) * KC * 4 + lq) * 128 + l15 * 8;
#pragma unroll
  for (int j = 0; j < 4; ++j)
    boff[j] = ((size_t)(((n0 + wn) >> 4) + j) * KC * 4 + lq) * 128 + l15 * 8;

  f32x4 acc[4][4] = {};
  Frags f0, f1;

  auto load = [&](Frags& f, int q) {
    const size_t dq = (size_t)q * 512;
#pragma unroll
    for (int i = 0; i < 4; ++i) {
      f.ah[i] = *(const short8*)(xh + aoff[i] + dq);
      f.al[i] = *(const short8*)(xl + aoff[i] + dq);
    }
#pragma unroll
    for (int j = 0; j < 4; ++j) {
      f.bh[j] = *(const short8*)(wh + boff[j] + dq);
      f.bl[j] = *(const short8*)(wl + boff[j] + dq);
    }
  };
  auto step = [&](const Frags& f) {
#pragma unroll
    for (int i = 0; i < 4; ++i)
#pragma unroll
      for (int j = 0; j < 4; ++j) {
        acc[i][j] = __builtin_amdgcn_mfma_f32_16x16x32_bf16(f.ah[i], f.bh[j], acc[i][j], 0, 0, 0);
        acc[i][j] = __builtin_amdgcn_mfma_f32_16x16x32_bf16(f.ah[i], f.bl[j], acc[i][j], 0, 0, 0);
        acc[i][j] = __builtin_amdgcn_mfma_f32_16x16x32_bf16(f.al[i], f.bh[j], acc[i][j], 0, 0, 0);
      }
  };

  load(f0, 0);
#pragma unroll 1
  for (int q = 0; q < KC; q += 2) {
    load(f1, q + 1);
    step(f0);
    if (q + 2 < KC) load(f0, q + 2);
    step(f1);
  }

  __shared__ float red[128][33];
#pragma unroll
  for (int i = 0; i < 4; ++i)
#pragma unroll
    for (int r = 0; r < 4; ++r) {
      const int row = wm + i * 16 + lq * 4 + r;
      float s = 0.f;
#pragma unroll
      for (int j = 0; j < 4; ++j) s += acc[i][j][r] * acc[i][j][r];
      red[row][(l15 << 1) | (wave >> 1)] = s;
    }
  __syncthreads();
  if (tid < 128) {
    float s = 0.f;
#pragma unroll
    for (int c = 0; c < 32; ++c) s += red[tid][c];
    atomicAdd(&sc_raw[m0 + tid], s);
  }
}

// ---------------------------------------------------------------------------
// M = wo @ wjv, split-precision direct-frag GEMM.  64x64 tiles -> 256 blocks
// (full CU occupancy; was 64 blocks @128x128 = 25% busy).  Output: bf16 M in
// A-FRAG layout [f][k] (KC=32) so the WT GEMM can load it directly.
// ---------------------------------------------------------------------------
struct Frags2 { short8 ah[2], al[2], bh[2], bl[2]; };

__global__ __launch_bounds__(256, 2) void gemm_m_split(
    const ushort* __restrict__ ah_, const ushort* __restrict__ al_,
    const ushort* __restrict__ bh_, const ushort* __restrict__ bl_,
    ushort* __restrict__ Mf)
{
  const int tid = threadIdx.x;
  const int m0 = blockIdx.y * 64, n0 = blockIdx.x * 64;
  const int wave = tid >> 6, lane = tid & 63;
  const int l15 = lane & 15, lq = lane >> 4;
  const int wm = (wave & 1) * 32, wn = (wave >> 1) * 32;

  size_t aoff[2], boff[2];
#pragma unroll
  for (int i = 0; i < 2; ++i)
    aoff[i] = ((size_t)(((m0 + wm) >> 4) + i) * KC * 4 + lq) * 128 + l15 * 8;
#pragma unroll
  for (int j = 0; j < 2; ++j)
    boff[j] = ((size_t)(((n0 + wn) >> 4) + j) * KC * 4 + lq) * 128 + l15 * 8;

  f32x4 acc[2][2] = {};
  Frags2 f0, f1;

  auto load = [&](Frags2& f, int q) {
    const size_t dq = (size_t)q * 512;
#pragma unroll
    for (int i = 0; i < 2; ++i) {
      f.ah[i] = *(const short8*)(ah_ + aoff[i] + dq);
      f.al[i] = *(const short8*)(al_ + aoff[i] + dq);
    }
#pragma unroll
    for (int j = 0; j < 2; ++j) {
      f.bh[j] = *(const short8*)(bh_ + boff[j] + dq);
      f.bl[j] = *(const short8*)(bl_ + boff[j] + dq);
    }
  };
  auto step = [&](const Frags2& f) {
#pragma unroll
    for (int i = 0; i < 2; ++i)
#pragma unroll
      for (int j = 0; j < 2; ++j) {
        acc[i][j] = __builtin_amdgcn_mfma_f32_16x16x32_bf16(f.ah[i], f.bh[j], acc[i][j], 0, 0, 0);
        acc[i][j] = __builtin_amdgcn_mfma_f32_16x16x32_bf16(f.ah[i], f.bl[j], acc[i][j], 0, 0, 0);
        acc[i][j] = __builtin_amdgcn_mfma_f32_16x16x32_bf16(f.al[i], f.bh[j], acc[i][j], 0, 0, 0);
      }
  };

  load(f0, 0);
#pragma unroll 1
  for (int q = 0; q < KC; q += 2) {
    load(f1, q + 1);
    step(f0);
    if (q + 2 < KC) load(f0, q + 2);
    step(f1);
  }

  // Epilogue: write bf16 M in frag layout off(f, k) with KC=32.
#pragma unroll
  for (int i = 0; i < 2; ++i)
#pragma unroll
    for (int j = 0; j < 2; ++j) {
      const int fb = m0 + wm + i * 16 + lq * 4;
      const int k  = n0 + wn + j * 16 + l15;
#pragma unroll
      for (int r = 0; r < 4; ++r) {
        const int f = fb + r;
        const size_t addr =
            (((size_t)(f >> 4) * KC + (k >> 5)) * 4 + ((k >> 3) & 3)) * 128 +
            (f & 15) * 8 + (k & 7);
        Mf[addr] = f2bf(acc[i][j][r]);
      }
    }
}

// ---------------------------------------------------------------------------
// sc = sc_raw/32; pmax = inclusive prefix max per batch (unchanged).
// ---------------------------------------------------------------------------
__global__ __launch_bounds__(1024) void scan_max(
    const float* __restrict__ sc_raw, float* __restrict__ sc,
    float* __restrict__ pmax)
{
  const int b = blockIdx.x;
  __shared__ float b0[T_SEQ];
  __shared__ float b1[T_SEQ];
  const int tid = threadIdx.x;
  for (int i = tid; i < T_SEQ; i += 1024) {
    const float v = sc_raw[b*T_SEQ + i] * 0.03125f;
    b0[i] = v;
    sc[b*T_SEQ + i] = v;
  }
  __syncthreads();
  float* src = b0; float* dst = b1;
  for (int off = 1; off < T_SEQ; off <<= 1) {
    for (int i = tid; i < T_SEQ; i += 1024)
      dst[i] = (i >= off) ? fmaxf(src[i], src[i - off]) : src[i];
    __syncthreads();
    float* tmp = src; src = dst; dst = tmp;
  }
  for (int i = tid; i < T_SEQ; i += 1024) pmax[b*T_SEQ + i] = src[i];
}

// ---------------------------------------------------------------------------
// zinv[r] = 1 / sum_{s<=t} exp(st*(sc_s - pm_t)).  One wave per row.
// ---------------------------------------------------------------------------
__global__ __launch_bounds__(256) void zgen(
    const float* __restrict__ sc, const float* __restrict__ pmax,
    float* __restrict__ zinv)
{
  const int row = blockIdx.x * 4 + (threadIdx.x >> 6);
  const int lane = threadIdx.x & 63;
  const int t = row & (T_SEQ - 1);
  const int base = row & ~(T_SEQ - 1);
  const float st = sc[row], pm = pmax[row];
  float z = 0.f;
  for (int s = lane; s <= t; s += 64)
    z += __expf(st * (sc[base + s] - pm));
#pragma unroll
  for (int m = 1; m < 64; m <<= 1) z += __shfl_xor(z, m);
  if (lane == 0) zinv[row] = 1.0f / z;
}

// ---------------------------------------------------------------------------
// P generation, ONCE (not 8x): bf16 P in packed A-frag layout.
// Batch b, supertile P (128 rows): 8 rowblocks x W=(4P+4) chunks, chunk base
// = 16*P*(P+1) + pr*W + q.  Element (t = P*128+pr*16+l, s = q*32+hi*8+e) at
// chunkbase*512 + hi*128 + l*8 + e.  Grid (y=8, b=4, z=4); supertiles paired
// (15-y, y) for load balance; z splits the unit range.
// ---------------------------------------------------------------------------
__global__ __launch_bounds__(512) void pgen(
    const float* __restrict__ sc, const float* __restrict__ pmax,
    ushort* __restrict__ P012, ushort* __restrict__ P3)
{
  const int y = blockIdx.x, b = blockIdx.y, zslice = blockIdx.z;
  const int bT = b * T_SEQ;
  ushort* pb = (b < 3) ? P012 + (size_t)b * PBATCH_ELEMS : P3;
  __shared__ float scs[T_SEQ];
  __shared__ float pms[T_SEQ];
  const int tid = threadIdx.x;
  for (int i = tid; i < T_SEQ; i += 512) {
    scs[i] = sc[bT + i];
    pms[i] = pmax[bT + i];
  }
  __syncthreads();

#pragma unroll 1
  for (int ph = 0; ph < 2; ++ph) {
    const int P = ph ? y : 15 - y;
    const int W = 4 * P + 4;
    ushort* base = pb + (size_t)(16 * P * (P + 1)) * 512;
    const int nu = 512 * W;   // 16B units in this supertile
#pragma unroll 1
    for (int u = tid + zslice * 512; u < nu; u += 2048) {
      const int sub = u & 63, hi = sub >> 4, l = sub & 15;
      const int pr = (u >> 6) & 7, q = u >> 9;
      const int t = P * 128 + pr * 16 + l;
      const int s0 = q * 32 + hi * 8;
      const float st = scs[t], pm = pms[t];
      ushort tmp[8];
#pragma unroll
      for (int e = 0; e < 8; ++e) {
        const int s = s0 + e;
        float pe = 0.f;
        if (s <= t) pe = __expf(st * (scs[s] - pm));
        tmp[e] = f2bf(pe);
      }
      *(uint4*)&base[(size_t)(pr * W + q) * 512 + hi * 128 + l * 8] =
          *(const uint4*)tmp;
    }
  }
}

// ---------------------------------------------------------------------------
// WT[f][rg] = sum_k M[f][k]*x[rg][k], both operands direct from frag layout
// (no LDS, no barriers).  Output written in frag layout [f][rg] (KCR=256)
// so attn_gemm's B loads are 1KB-coalesced.
// ---------------------------------------------------------------------------
struct FragsP { short8 a[4], b[4]; };

__global__ __launch_bounds__(256, 2) void gemm_wt(
    const ushort* __restrict__ Af, const ushort* __restrict__ Bf,
    ushort* __restrict__ WT)
{
  const int tid = threadIdx.x;
  const int m0 = blockIdx.y * 128, n0 = blockIdx.x * 128;
  const int wave = tid >> 6, lane = tid & 63;
  const int l15 = lane & 15, lq = lane >> 4;
  const int wm = (wave & 1) * 64, wn = (wave >> 1) * 64;

  size_t aoff[4], boff[4];
#pragma unroll
  for (int i = 0; i < 4; ++i)
    aoff[i] = ((size_t)(((m0 + wm) >> 4) + i) * KC * 4 + lq) * 128 + l15 * 8;
#pragma unroll
  for (int j = 0; j < 4; ++j)
    boff[j] = ((size_t)(((n0 + wn) >> 4) + j) * KC * 4 + lq) * 128 + l15 * 8;

  f32x4 acc[4][4] = {};
  FragsP f0, f1;

  auto load = [&](FragsP& f, int q) {
    const size_t dq = (size_t)q * 512;
#pragma unroll
    for (int i = 0; i < 4; ++i) f.a[i] = *(const short8*)(Af + aoff[i] + dq);
#pragma unroll
    for (int j = 0; j < 4; ++j) f.b[j] = *(const short8*)(Bf + boff[j] + dq);
  };
  auto step = [&](const FragsP& f) {
#pragma unroll
    for (int i = 0; i < 4; ++i)
#pragma unroll
      for (int j = 0; j < 4; ++j)
        acc[i][j] = __builtin_amdgcn_mfma_f32_16x16x32_bf16(f.a[i], f.b[j], acc[i][j], 0, 0, 0);
  };

  load(f0, 0);
#pragma unroll 1
  for (int q = 0; q < KC; q += 2) {
    load(f1, q + 1);
    step(f0);
    if (q + 2 < KC) load(f0, q + 2);
    step(f1);
  }

  // Epilogue: frag-layout store off(e, rg) with KCR=256.
#pragma unroll
  for (int i = 0; i < 4; ++i)
#pragma unroll
    for (int j = 0; j < 4; ++j) {
      const int eb = m0 + wm + i * 16 + lq * 4;
      const int rg = n0 + wn + j * 16 + l15;
#pragma unroll
      for (int r = 0; r < 4; ++r) {
        const int e = eb + r;
        const size_t addr =
            (((size_t)(e >> 4) * KCR + (rg >> 5)) * 4 + ((rg >> 3) & 3)) * 128 +
            (e & 15) * 8 + (rg & 7);
        WT[addr] = f2bf(acc[i][j][r]);
      }
    }
}

// ---------------------------------------------------------------------------
// Attention as a pure direct-frag GEMM over the causal triangle:
//   out[t][e] = zinv[t] * sum_s P[t][s] * W[s][e]
// A = packed P frags, B = WT frags; no LDS, no barriers in the K-loop.
// Grid (8 e-tiles, 8 y, 4 b); per block two phases ty = 15-y then y, so every
// block does 68 k-chunks total (perfect balance).
// ---------------------------------------------------------------------------
__global__ __launch_bounds__(256, 2) void attn_gemm(
    const ushort* __restrict__ P012, const ushort* __restrict__ P3,
    const ushort* __restrict__ WT, const float* __restrict__ zinv,
    float* __restrict__ outp)
{
  const int b = blockIdx.z, y = blockIdx.y;
  const int e0 = blockIdx.x * 128;
  const int bT = b * T_SEQ;
  const ushort* pb = (b < 3) ? P012 + (size_t)b * PBATCH_ELEMS : P3;
  const int tid = threadIdx.x;
  const int wave = tid >> 6, lane = tid & 63;
  const int l15 = lane & 15, lq = lane >> 4;
  const int wm = (wave & 1) * 64, wn = (wave >> 1) * 64;

  size_t boff[4];
#pragma unroll
  for (int j = 0; j < 4; ++j)
    boff[j] = ((size_t)((((e0 + wn) >> 4) + j) * KCR + (bT >> 5)) * 4 + lq) * 128
              + l15 * 8;

#pragma unroll 1
  for (int ph = 0; ph < 2; ++ph) {
    const int ty = ph ? y : 15 - y;
    const int W = 4 * ty + 4;
    const int t0 = ty * 128;

    size_t aoff[4];
#pragma unroll
    for (int i = 0; i < 4; ++i)
      aoff[i] = ((size_t)(16 * ty * (ty + 1)) + (size_t)((wm >> 4) + i) * W) * 512
                + lq * 128 + l15 * 8;

    f32x4 acc[4][4] = {};
    FragsP f0, f1;

    auto load = [&](FragsP& f, int q) {
      const size_t dq = (size_t)q * 512;
#pragma unroll
      for (int i = 0; i < 4; ++i) f.a[i] = *(const short8*)(pb + aoff[i] + dq);
#pragma unroll
      for (int j = 0; j < 4; ++j) f.b[j] = *(const short8*)(WT + boff[j] + dq);
    };
    auto step = [&](const FragsP& f) {
#pragma unroll
      for (int i = 0; i < 4; ++i)
#pragma unroll
        for (int j = 0; j < 4; ++j)
          acc[i][j] = __builtin_amdgcn_mfma_f32_16x16x32_bf16(f.a[i], f.b[j], acc[i][j], 0, 0, 0);
    };

    load(f0, 0);
#pragma unroll 1
    for (int q = 0; q < W; q += 2) {   // W is a multiple of 4
      load(f1, q + 1);
      step(f0);
      if (q + 2 < W) load(f0, q + 2);
      step(f1);
    }

    // Epilogue: scale by zinv, write fp32 final output.
#pragma unroll
    for (int i = 0; i < 4; ++i)
#pragma unroll
      for (int r = 0; r < 4; ++r) {
        const int row = t0 + wm + i * 16 + lq * 4 + r;
        const float zi = zinv[bT + row];
#pragma unroll
        for (int j = 0; j < 4; ++j) {
          const int nb = e0 + wn + j * 16 + l15;
          outp[(size_t)(bT + row) * E_DIM + nb] = acc[i][j][r] * zi;
        }
      }
  }
}

// ---------------------------------------------------------------------------
extern "C" void kernel_launch(void* const* d_in, const int* in_sizes, int n_in,
                              void* d_out, int out_size, void* d_ws, size_t ws_size,
                              hipStream_t stream) {
  (void)in_sizes; (void)n_in; (void)out_size; (void)ws_size;
  const float* x   = (const float*)d_in[0];
  const float* wj  = (const float*)d_in[1];
  const float* wjv = (const float*)d_in[2];
  const float* wo  = (const float*)d_in[3];
  float* out = (float*)d_out;

  ushort* xh_f  = (ushort*)d_ws;                        // 16.8 MB frag; later P(b0..2)
  ushort* xl_f  = xh_f  + (size_t)R_ROWS * E_DIM;       // 16.8 MB frag; later WT
  ushort* bufA  = xl_f  + (size_t)R_ROWS * E_DIM;       // 2 MB: wo_h, then wj_h, then P(b3)
  ushort* bufB  = bufA  + (size_t)E_DIM * E_DIM;        // 2 MB: wo_l, then wj_l
  ushort* bufC  = bufB  + (size_t)E_DIM * E_DIM;        // 2 MB: wjv^T_h
  ushort* bufD  = bufC  + (size_t)E_DIM * E_DIM;        // 2 MB: wjv^T_l
  ushort* Mf    = bufD  + (size_t)E_DIM * E_DIM;        // 2 MB: bf16 M frags
  float* sc_raw = (float*)(Mf + (size_t)E_DIM * E_DIM);
  float* sc     = sc_raw + R_ROWS;
  float* pmax   = sc + R_ROWS;
  float* zinv   = pmax + R_ROWS;
  ushort* WT    = xl_f;     // xl_f dead after gemm_sq_direct (stream-serial)
  ushort* P012  = xh_f;     // xh_f dead after gemm_wt (3 x 4.46 MB <= 16.8 MB)
  ushort* P3    = bufA;     // bufA..Mf (10 MB) dead after gemm_wt

  hipMemsetAsync(sc_raw, 0, R_ROWS * sizeof(float), stream);

  // --- M = wo @ wjv (split-precision), Mf = bf16 M in frag layout ----------
  cvt_split_frag <<<E_DIM*E_DIM/8/256, 256, 0, stream>>>(wo,  bufA, bufB, E_DIM*E_DIM/8);
  cvt_splitT_frag<<<E_DIM*E_DIM/8/256, 256, 0, stream>>>(wjv, bufC, bufD, E_DIM*E_DIM/8);
  gemm_m_split<<<dim3(E_DIM/64, E_DIM/64), 256, 0, stream>>>(bufA, bufB, bufC, bufD, Mf);

  // --- x and wj split frags (wj frags overwrite the dead wo frags) ---------
  cvt_split_frag<<<R_ROWS*E_DIM/8/256, 256, 0, stream>>>(x,  xh_f, xl_f, R_ROWS*E_DIM/8);
  cvt_split_frag<<<E_DIM*E_DIM/8/256, 256, 0, stream>>>(wj, bufA, bufB, E_DIM*E_DIM/8);

  // sc_raw[r] = ||x_r @ wj^T||^2
  gemm_sq_direct<<<dim3(E_DIM/128, R_ROWS/128), 256, 0, stream>>>(
      xh_f, xl_f, bufA, bufB, sc_raw);
  scan_max<<<4, 1024, 0, stream>>>(sc_raw, sc, pmax);
  zgen<<<R_ROWS/4, 256, 0, stream>>>(sc, pmax, zinv);

  // WT[f][rg] = sum_k M[f][k]*x[rg][k]  (direct frags both sides, frag out)
  gemm_wt<<<dim3(R_ROWS/128, E_DIM/128), 256, 0, stream>>>(Mf, xh_f, WT);

  // P once, packed frag layout (xh_f + bufA regions now dead)
  pgen<<<dim3(8, 4, 4), 512, 0, stream>>>(sc, pmax, P012, P3);

  // out[t][e] = zinv[t] * sum_s P[t][s] * W[s][e]   (fp32 final output)
  attn_gemm<<<dim3(E_DIM/128, 8, 4), 256, 0, stream>>>(P012, P3, WT, zinv, out);
}

// Round 4
// 268.332 us; speedup vs baseline: 1.0484x; 1.0255x over previous
//
#include <hip/hip_runtime.h>
#include <math.h>

// B=4, T=2048, E=1024, H*D=1024; R = B*T = 8192.  K is always 1024.
#define R_ROWS 8192
#define T_SEQ  2048
#define E_DIM  1024
#define KC     32          // K/32 chunks for K=1024
#define KCR    256         // K/32 chunks for K=8192 (WT frag layout)
// Packed P storage: per batch, supertile P (128 rows) has 8 rowblocks x (4P+4)
// chunks; total chunks = sum_{P=0..15} 8*(4P+4) = 4352; each chunk = 512 elems.
#define PBATCH_ELEMS ((size_t)4352 * 512)

typedef __attribute__((ext_vector_type(8))) short short8;
typedef __attribute__((ext_vector_type(4))) float f32x4;

__device__ __forceinline__ ushort f2bf(float f) {
  uint u = __float_as_uint(f);
  u += 0x7FFFu + ((u >> 16) & 1u);   // round-to-nearest-even
  return (ushort)(u >> 16);
}
__device__ __forceinline__ float bf2f(ushort h) {
  return __uint_as_float(((uint)h) << 16);
}

// ---------------------------------------------------------------------------
// MFMA A/B fragment layout for a [R][K] bf16 matrix (KCx = K/32):
//   off(r,k) = (((r>>4)*KCx + (k>>5))*4 + ((k>>3)&3))*128 + (r&15)*8 + (k&7)
// ---------------------------------------------------------------------------

__device__ __forceinline__ void split_frag_unit(
    const float* __restrict__ in, ushort* __restrict__ hi,
    ushort* __restrict__ lo, int g)
{
  const int l = g & 15, h = (g >> 4) & 3;
  const int pq = g >> 6;
  const int q = pq & (KC - 1), p = pq >> 5;
  const size_t src = (size_t)(p * 16 + l) * 1024 + q * 32 + h * 8;
  const float4 v0 = *(const float4*)&in[src];
  const float4 v1 = *(const float4*)&in[src + 4];
  ushort hh[8], ll[8];
  const float v[8] = {v0.x, v0.y, v0.z, v0.w, v1.x, v1.y, v1.z, v1.w};
#pragma unroll
  for (int e = 0; e < 8; ++e) {
    hh[e] = f2bf(v[e]);
    ll[e] = f2bf(v[e] - bf2f(hh[e]));
  }
  *(uint4*)&hi[(size_t)g * 8] = *(const uint4*)hh;
  *(uint4*)&lo[(size_t)g * 8] = *(const uint4*)ll;
}

__device__ __forceinline__ void splitT_frag_unit(
    const float* __restrict__ in, ushort* __restrict__ hi,
    ushort* __restrict__ lo, int g)
{
  const int l = g & 15, h = (g >> 4) & 3;
  const int pq = g >> 6;
  const int q = pq & (KC - 1), p = pq >> 5;
  const int rr = p * 16 + l;          // logical row (k index of M's B-side)
  const int cc = q * 32 + h * 8;      // reduction col (e index)
  ushort hh[8], ll[8];
#pragma unroll
  for (int e = 0; e < 8; ++e) {
    const float v = in[(size_t)(cc + e) * 1024 + rr];
    hh[e] = f2bf(v);
    ll[e] = f2bf(v - bf2f(hh[e]));
  }
  *(uint4*)&hi[(size_t)g * 8] = *(const uint4*)hh;
  *(uint4*)&lo[(size_t)g * 8] = *(const uint4*)ll;
}

// fp32 [R][1024] -> (hi, lo) bf16 fragment layout (for x).
__global__ __launch_bounds__(256) void cvt_split_frag(
    const float* __restrict__ in, ushort* __restrict__ hi,
    ushort* __restrict__ lo, int n)
{
  int g = blockIdx.x * 256 + threadIdx.x;
  if (g >= n) return;
  split_frag_unit(in, hi, lo, g);
}

// All three weight conversions in ONE launch (1536 blocks).
__global__ __launch_bounds__(256) void cvt_weights(
    const float* __restrict__ wo, const float* __restrict__ wjv,
    const float* __restrict__ wj,
    ushort* __restrict__ woh, ushort* __restrict__ wol,
    ushort* __restrict__ wjvh, ushort* __restrict__ wjvl,
    ushort* __restrict__ wjh, ushort* __restrict__ wjl)
{
  const int blk = blockIdx.x;
  const int g = (blk & 511) * 256 + threadIdx.x;
  if (blk < 512)            split_frag_unit (wo,  woh,  wol,  g);
  else if (blk < 1024)      splitT_frag_unit(wjv, wjvh, wjvl, g);
  else                      split_frag_unit (wj,  wjh,  wjl,  g);
}

// ---------------------------------------------------------------------------
// Split-bf16 sc kernel, LDS-FREE K-loop (unchanged).
// ---------------------------------------------------------------------------
struct Frags { short8 ah[4], al[4], bh[4], bl[4]; };

__global__ __launch_bounds__(256, 2) void gemm_sq_direct(
    const ushort* __restrict__ xh, const ushort* __restrict__ xl,
    const ushort* __restrict__ wh, const ushort* __restrict__ wl,
    float* __restrict__ sc_raw)
{
  const int tid = threadIdx.x;
  const int m0 = blockIdx.y * 128, n0 = blockIdx.x * 128;
  const int wave = tid >> 6, lane = tid & 63;
  const int l15 = lane & 15, lq = lane >> 4;
  const int wm = (wave & 1) * 64, wn = (wave >> 1) * 64;

  size_t aoff[4], boff[4];
#pragma unroll
  for (int i = 0; i < 4; ++i)
    aoff[i] = ((size_t)(((m0 + wm) >> 4) + i) * KC * 4 + lq) * 128 + l15 * 8;
#pragma unroll
  for (int j = 0; j < 4; ++j)
    boff[j] = ((size_t)(((n0 + wn) >> 4) + j) * KC * 4 + lq) * 128 + l15 * 8;

  f32x4 acc[4][4] = {};
  Frags f0, f1;

  auto load = [&](Frags& f, int q) {
    const size_t dq = (size_t)q * 512;
#pragma unroll
    for (int i = 0; i < 4; ++i) {
      f.ah[i] = *(const short8*)(xh + aoff[i] + dq);
      f.al[i] = *(const short8*)(xl + aoff[i] + dq);
    }
#pragma unroll
    for (int j = 0; j < 4; ++j) {
      f.bh[j] = *(const short8*)(wh + boff[j] + dq);
      f.bl[j] = *(const short8*)(wl + boff[j] + dq);
    }
  };
  auto step = [&](const Frags& f) {
#pragma unroll
    for (int i = 0; i < 4; ++i)
#pragma unroll
      for (int j = 0; j < 4; ++j) {
        acc[i][j] = __builtin_amdgcn_mfma_f32_16x16x32_bf16(f.ah[i], f.bh[j], acc[i][j], 0, 0, 0);
        acc[i][j] = __builtin_amdgcn_mfma_f32_16x16x32_bf16(f.ah[i], f.bl[j], acc[i][j], 0, 0, 0);
        acc[i][j] = __builtin_amdgcn_mfma_f32_16x16x32_bf16(f.al[i], f.bh[j], acc[i][j], 0, 0, 0);
      }
  };

  load(f0, 0);
#pragma unroll 1
  for (int q = 0; q < KC; q += 2) {
    load(f1, q + 1);
    step(f0);
    if (q + 2 < KC) load(f0, q + 2);
    step(f1);
  }

  __shared__ float red[128][33];
#pragma unroll
  for (int i = 0; i < 4; ++i)
#pragma unroll
    for (int r = 0; r < 4; ++r) {
      const int row = wm + i * 16 + lq * 4 + r;
      float s = 0.f;
#pragma unroll
      for (int j = 0; j < 4; ++j) s += acc[i][j][r] * acc[i][j][r];
      red[row][(l15 << 1) | (wave >> 1)] = s;
    }
  __syncthreads();
  if (tid < 128) {
    float s = 0.f;
#pragma unroll
    for (int c = 0; c < 32; ++c) s += red[tid][c];
    atomicAdd(&sc_raw[m0 + tid], s);
  }
}

// ---------------------------------------------------------------------------
// M = wo @ wjv, split-precision direct-frag GEMM.  64x64 tiles, 256 blocks.
// Output: bf16 M in A-FRAG layout [f][k] (KC=32).
// ---------------------------------------------------------------------------
struct Frags2 { short8 ah[2], al[2], bh[2], bl[2]; };

__global__ __launch_bounds__(256, 2) void gemm_m_split(
    const ushort* __restrict__ ah_, const ushort* __restrict__ al_,
    const ushort* __restrict__ bh_, const ushort* __restrict__ bl_,
    ushort* __restrict__ Mf)
{
  const int tid = threadIdx.x;
  const int m0 = blockIdx.y * 64, n0 = blockIdx.x * 64;
  const int wave = tid >> 6, lane = tid & 63;
  const int l15 = lane & 15, lq = lane >> 4;
  const int wm = (wave & 1) * 32, wn = (wave >> 1) * 32;

  size_t aoff[2], boff[2];
#pragma unroll
  for (int i = 0; i < 2; ++i)
    aoff[i] = ((size_t)(((m0 + wm) >> 4) + i) * KC * 4 + lq) * 128 + l15 * 8;
#pragma unroll
  for (int j = 0; j < 2; ++j)
    boff[j] = ((size_t)(((n0 + wn) >> 4) + j) * KC * 4 + lq) * 128 + l15 * 8;

  f32x4 acc[2][2] = {};
  Frags2 f0, f1;

  auto load = [&](Frags2& f, int q) {
    const size_t dq = (size_t)q * 512;
#pragma unroll
    for (int i = 0; i < 2; ++i) {
      f.ah[i] = *(const short8*)(ah_ + aoff[i] + dq);
      f.al[i] = *(const short8*)(al_ + aoff[i] + dq);
    }
#pragma unroll
    for (int j = 0; j < 2; ++j) {
      f.bh[j] = *(const short8*)(bh_ + boff[j] + dq);
      f.bl[j] = *(const short8*)(bl_ + boff[j] + dq);
    }
  };
  auto step = [&](const Frags2& f) {
#pragma unroll
    for (int i = 0; i < 2; ++i)
#pragma unroll
      for (int j = 0; j < 2; ++j) {
        acc[i][j] = __builtin_amdgcn_mfma_f32_16x16x32_bf16(f.ah[i], f.bh[j], acc[i][j], 0, 0, 0);
        acc[i][j] = __builtin_amdgcn_mfma_f32_16x16x32_bf16(f.ah[i], f.bl[j], acc[i][j], 0, 0, 0);
        acc[i][j] = __builtin_amdgcn_mfma_f32_16x16x32_bf16(f.al[i], f.bh[j], acc[i][j], 0, 0, 0);
      }
  };

  load(f0, 0);
#pragma unroll 1
  for (int q = 0; q < KC; q += 2) {
    load(f1, q + 1);
    step(f0);
    if (q + 2 < KC) load(f0, q + 2);
    step(f1);
  }

#pragma unroll
  for (int i = 0; i < 2; ++i)
#pragma unroll
    for (int j = 0; j < 2; ++j) {
      const int fb = m0 + wm + i * 16 + lq * 4;
      const int k  = n0 + wn + j * 16 + l15;
#pragma unroll
      for (int r = 0; r < 4; ++r) {
        const int f = fb + r;
        const size_t addr =
            (((size_t)(f >> 4) * KC + (k >> 5)) * 4 + ((k >> 3) & 3)) * 128 +
            (f & 15) * 8 + (k & 7);
        Mf[addr] = f2bf(acc[i][j][r]);
      }
    }
}

// ---------------------------------------------------------------------------
// sc = sc_raw/32; pmax = inclusive prefix max per batch (unchanged).
// ---------------------------------------------------------------------------
__global__ __launch_bounds__(1024) void scan_max(
    const float* __restrict__ sc_raw, float* __restrict__ sc,
    float* __restrict__ pmax)
{
  const int b = blockIdx.x;
  __shared__ float b0[T_SEQ];
  __shared__ float b1[T_SEQ];
  const int tid = threadIdx.x;
  for (int i = tid; i < T_SEQ; i += 1024) {
    const float v = sc_raw[b*T_SEQ + i] * 0.03125f;
    b0[i] = v;
    sc[b*T_SEQ + i] = v;
  }
  __syncthreads();
  float* src = b0; float* dst = b1;
  for (int off = 1; off < T_SEQ; off <<= 1) {
    for (int i = tid; i < T_SEQ; i += 1024)
      dst[i] = (i >= off) ? fmaxf(src[i], src[i - off]) : src[i];
    __syncthreads();
    float* tmp = src; src = dst; dst = tmp;
  }
  for (int i = tid; i < T_SEQ; i += 1024) pmax[b*T_SEQ + i] = src[i];
}

// ---------------------------------------------------------------------------
// zinv[r] = 1 / sum_{s<=t} exp(st*(sc_s - pm_t)).  One wave per row.
// ---------------------------------------------------------------------------
__global__ __launch_bounds__(256) void zgen(
    const float* __restrict__ sc, const float* __restrict__ pmax,
    float* __restrict__ zinv)
{
  const int row = blockIdx.x * 4 + (threadIdx.x >> 6);
  const int lane = threadIdx.x & 63;
  const int t = row & (T_SEQ - 1);
  const int base = row & ~(T_SEQ - 1);
  const float st = sc[row], pm = pmax[row];
  float z = 0.f;
  for (int s = lane; s <= t; s += 64)
    z += __expf(st * (sc[base + s] - pm));
#pragma unroll
  for (int m = 1; m < 64; m <<= 1) z += __shfl_xor(z, m);
  if (lane == 0) zinv[row] = 1.0f / z;
}

// ---------------------------------------------------------------------------
// P generation, ONCE: bf16 P in packed A-frag layout (unchanged).
// ---------------------------------------------------------------------------
__global__ __launch_bounds__(512) void pgen(
    const float* __restrict__ sc, const float* __restrict__ pmax,
    ushort* __restrict__ P012, ushort* __restrict__ P3)
{
  const int y = blockIdx.x, b = blockIdx.y, zslice = blockIdx.z;
  const int bT = b * T_SEQ;
  ushort* pb = (b < 3) ? P012 + (size_t)b * PBATCH_ELEMS : P3;
  __shared__ float scs[T_SEQ];
  __shared__ float pms[T_SEQ];
  const int tid = threadIdx.x;
  for (int i = tid; i < T_SEQ; i += 512) {
    scs[i] = sc[bT + i];
    pms[i] = pmax[bT + i];
  }
  __syncthreads();

#pragma unroll 1
  for (int ph = 0; ph < 2; ++ph) {
    const int P = ph ? y : 15 - y;
    const int W = 4 * P + 4;
    ushort* base = pb + (size_t)(16 * P * (P + 1)) * 512;
    const int nu = 512 * W;   // 16B units in this supertile
#pragma unroll 1
    for (int u = tid + zslice * 512; u < nu; u += 2048) {
      const int sub = u & 63, hi = sub >> 4, l = sub & 15;
      const int pr = (u >> 6) & 7, q = u >> 9;
      const int t = P * 128 + pr * 16 + l;
      const int s0 = q * 32 + hi * 8;
      const float st = scs[t], pm = pms[t];
      ushort tmp[8];
#pragma unroll
      for (int e = 0; e < 8; ++e) {
        const int s = s0 + e;
        float pe = 0.f;
        if (s <= t) pe = __expf(st * (scs[s] - pm));
        tmp[e] = f2bf(pe);
      }
      *(uint4*)&base[(size_t)(pr * W + q) * 512 + hi * 128 + l * 8] =
          *(const uint4*)tmp;
    }
  }
}

// ---------------------------------------------------------------------------
// WT[f][rg] = sum_k M[f][k]*x[rg][k], direct frag both sides (unchanged).
// ---------------------------------------------------------------------------
struct FragsP { short8 a[4], b[4]; };

__global__ __launch_bounds__(256, 2) void gemm_wt(
    const ushort* __restrict__ Af, const ushort* __restrict__ Bf,
    ushort* __restrict__ WT)
{
  const int tid = threadIdx.x;
  const int m0 = blockIdx.y * 128, n0 = blockIdx.x * 128;
  const int wave = tid >> 6, lane = tid & 63;
  const int l15 = lane & 15, lq = lane >> 4;
  const int wm = (wave & 1) * 64, wn = (wave >> 1) * 64;

  size_t aoff[4], boff[4];
#pragma unroll
  for (int i = 0; i < 4; ++i)
    aoff[i] = ((size_t)(((m0 + wm) >> 4) + i) * KC * 4 + lq) * 128 + l15 * 8;
#pragma unroll
  for (int j = 0; j < 4; ++j)
    boff[j] = ((size_t)(((n0 + wn) >> 4) + j) * KC * 4 + lq) * 128 + l15 * 8;

  f32x4 acc[4][4] = {};
  FragsP f0, f1;

  auto load = [&](FragsP& f, int q) {
    const size_t dq = (size_t)q * 512;
#pragma unroll
    for (int i = 0; i < 4; ++i) f.a[i] = *(const short8*)(Af + aoff[i] + dq);
#pragma unroll
    for (int j = 0; j < 4; ++j) f.b[j] = *(const short8*)(Bf + boff[j] + dq);
  };
  auto step = [&](const FragsP& f) {
#pragma unroll
    for (int i = 0; i < 4; ++i)
#pragma unroll
      for (int j = 0; j < 4; ++j)
        acc[i][j] = __builtin_amdgcn_mfma_f32_16x16x32_bf16(f.a[i], f.b[j], acc[i][j], 0, 0, 0);
  };

  load(f0, 0);
#pragma unroll 1
  for (int q = 0; q < KC; q += 2) {
    load(f1, q + 1);
    step(f0);
    if (q + 2 < KC) load(f0, q + 2);
    step(f1);
  }

#pragma unroll
  for (int i = 0; i < 4; ++i)
#pragma unroll
    for (int j = 0; j < 4; ++j) {
      const int eb = m0 + wm + i * 16 + lq * 4;
      const int rg = n0 + wn + j * 16 + l15;
#pragma unroll
      for (int r = 0; r < 4; ++r) {
        const int e = eb + r;
        const size_t addr =
            (((size_t)(e >> 4) * KCR + (rg >> 5)) * 4 + ((rg >> 3) & 3)) * 128 +
            (e & 15) * 8 + (rg & 7);
        WT[addr] = f2bf(acc[i][j][r]);
      }
    }
}

// ---------------------------------------------------------------------------
// Attention GEMM over the causal triangle, 512 threads / 8 waves per block.
// Waves: 2 (t-halves) x 4 (e-quarters); wave = 64t x 32e, acc[4][2].
// ---------------------------------------------------------------------------
struct Frags6 { short8 a[4], b[2]; };

__global__ __launch_bounds__(512) void attn_gemm(
    const ushort* __restrict__ P012, const ushort* __restrict__ P3,
    const ushort* __restrict__ WT, const float* __restrict__ zinv,
    float* __restrict__ outp)
{
  const int b = blockIdx.z, y = blockIdx.y;
  const int e0 = blockIdx.x * 128;
  const int bT = b * T_SEQ;
  const ushort* pb = (b < 3) ? P012 + (size_t)b * PBATCH_ELEMS : P3;
  const int tid = threadIdx.x;
  const int wave = tid >> 6, lane = tid & 63;
  const int l15 = lane & 15, lq = lane >> 4;
  const int wm = (wave & 1) * 64;       // t-offset within 128
  const int wn = (wave >> 1) * 32;      // e-offset within 128

  size_t boff[2];
#pragma unroll
  for (int j = 0; j < 2; ++j)
    boff[j] = ((size_t)((((e0 + wn) >> 4) + j) * KCR + (bT >> 5)) * 4 + lq) * 128
              + l15 * 8;

#pragma unroll 1
  for (int ph = 0; ph < 2; ++ph) {
    const int ty = ph ? y : 15 - y;
    const int W = 4 * ty + 4;
    const int t0 = ty * 128;

    size_t aoff[4];
#pragma unroll
    for (int i = 0; i < 4; ++i)
      aoff[i] = ((size_t)(16 * ty * (ty + 1)) + (size_t)((wm >> 4) + i) * W) * 512
                + lq * 128 + l15 * 8;

    f32x4 acc[4][2] = {};
    Frags6 f0, f1;

    auto load = [&](Frags6& f, int q) {
      const size_t dq = (size_t)q * 512;
#pragma unroll
      for (int i = 0; i < 4; ++i) f.a[i] = *(const short8*)(pb + aoff[i] + dq);
#pragma unroll
      for (int j = 0; j < 2; ++j) f.b[j] = *(const short8*)(WT + boff[j] + dq);
    };
    auto step = [&](const Frags6& f) {
#pragma unroll
      for (int i = 0; i < 4; ++i)
#pragma unroll
        for (int j = 0; j < 2; ++j)
          acc[i][j] = __builtin_amdgcn_mfma_f32_16x16x32_bf16(f.a[i], f.b[j], acc[i][j], 0, 0, 0);
    };

    load(f0, 0);
#pragma unroll 1
    for (int q = 0; q < W; q += 2) {   // W is a multiple of 4
      load(f1, q + 1);
      step(f0);
      if (q + 2 < W) load(f0, q + 2);
      step(f1);
    }

    // Epilogue: scale by zinv, write fp32 final output.
#pragma unroll
    for (int i = 0; i < 4; ++i)
#pragma unroll
      for (int r = 0; r < 4; ++r) {
        const int row = t0 + wm + i * 16 + lq * 4 + r;
        const float zi = zinv[bT + row];
#pragma unroll
        for (int j = 0; j < 2; ++j) {
          const int nb = e0 + wn + j * 16 + l15;
          outp[(size_t)(bT + row) * E_DIM + nb] = acc[i][j][r] * zi;
        }
      }
  }
}

// ---------------------------------------------------------------------------
extern "C" void kernel_launch(void* const* d_in, const int* in_sizes, int n_in,
                              void* d_out, int out_size, void* d_ws, size_t ws_size,
                              hipStream_t stream) {
  (void)in_sizes; (void)n_in; (void)out_size; (void)ws_size;
  const float* x   = (const float*)d_in[0];
  const float* wj  = (const float*)d_in[1];
  const float* wjv = (const float*)d_in[2];
  const float* wo  = (const float*)d_in[3];
  float* out = (float*)d_out;

  // All six weight frag buffers are live simultaneously now (fused cvt):
  ushort* xh_f  = (ushort*)d_ws;                        // 16.8 MB; later P(b0..2)
  ushort* xl_f  = xh_f  + (size_t)R_ROWS * E_DIM;       // 16.8 MB; later WT
  ushort* woh   = xl_f  + (size_t)R_ROWS * E_DIM;       // 2 MB, dead after gemm_m
  ushort* wol   = woh   + (size_t)E_DIM * E_DIM;        // 2 MB, dead after gemm_m
  ushort* wjvh  = wol   + (size_t)E_DIM * E_DIM;        // 2 MB, dead after gemm_m
  ushort* wjvl  = wjvh  + (size_t)E_DIM * E_DIM;        // 2 MB, dead after gemm_m
  ushort* wjh   = wjvl  + (size_t)E_DIM * E_DIM;        // 2 MB, dead after gemm_sq
  ushort* wjl   = wjh   + (size_t)E_DIM * E_DIM;        // 2 MB, dead after gemm_sq
  ushort* Mf    = wjl   + (size_t)E_DIM * E_DIM;        // 2 MB: bf16 M frags
  float* sc_raw = (float*)(Mf + (size_t)E_DIM * E_DIM);
  float* sc     = sc_raw + R_ROWS;
  float* pmax   = sc + R_ROWS;
  float* zinv   = pmax + R_ROWS;
  ushort* WT    = xl_f;     // xl_f dead after gemm_sq_direct (stream-serial)
  ushort* P012  = xh_f;     // xh_f dead after gemm_wt (3 x 4.46 MB <= 16.8 MB)
  ushort* P3    = woh;      // woh..wjl (12 MB) dead after gemm_sq/gemm_m

  hipMemsetAsync(sc_raw, 0, R_ROWS * sizeof(float), stream);

  // --- all weight cvts in one launch ---------------------------------------
  cvt_weights<<<1536, 256, 0, stream>>>(wo, wjv, wj,
                                        woh, wol, wjvh, wjvl, wjh, wjl);

  // M = wo @ wjv (split precision), bf16 frag-layout output
  gemm_m_split<<<dim3(E_DIM/64, E_DIM/64), 256, 0, stream>>>(
      woh, wol, wjvh, wjvl, Mf);

  // x split frags
  cvt_split_frag<<<R_ROWS*E_DIM/8/256, 256, 0, stream>>>(
      x, xh_f, xl_f, R_ROWS*E_DIM/8);

  // sc_raw[r] = ||x_r @ wj^T||^2
  gemm_sq_direct<<<dim3(E_DIM/128, R_ROWS/128), 256, 0, stream>>>(
      xh_f, xl_f, wjh, wjl, sc_raw);
  scan_max<<<4, 1024, 0, stream>>>(sc_raw, sc, pmax);
  zgen<<<R_ROWS/4, 256, 0, stream>>>(sc, pmax, zinv);

  // WT[f][rg] = sum_k M[f][k]*x[rg][k]  (frag-layout output)
  gemm_wt<<<dim3(R_ROWS/128, E_DIM/128), 256, 0, stream>>>(Mf, xh_f, WT);

  // P once, packed frag layout (xh_f + weight regions now dead)
  pgen<<<dim3(8, 4, 4), 512, 0, stream>>>(sc, pmax, P012, P3);

  // out[t][e] = zinv[t] * sum_s P[t][s] * W[s][e]   (8-wave blocks)
  attn_gemm<<<dim3(E_DIM/128, 8, 4), 512, 0, stream>>>(P012, P3, WT, zinv, out);
}